// Round 13
// baseline (69.476 us; speedup 1.0000x reference)
//
#include <hip/hip_runtime.h>
#include <hip/hip_bf16.h>
#include <hip/hip_fp16.h>

#define N_  4
#define C_  64
#define H_  28
#define W_  60
#define ZC_ 200
#define YC_ 8
#define XC_ 200
#define OUTC_ 128
#define KD_ 512            // C_*YC_
#define EPS_ 1e-6f
#define ZB 4               // z slices per block
#define XB 8               // x positions per block
#define NCOL 32            // ZB*XB columns per block

typedef __attribute__((ext_vector_type(8))) _Float16 half8;
typedef __attribute__((ext_vector_type(4))) float f32x4;

// ---------------------------------------------------------------------------
// Prep: featH[n][h][w][c] = f16(img[n][c][h][w])  (channels-last, f16)
//       WbH[o][y*64+c]    = f16(W[o][c*8+y])      (y-major k, f16)
// ---------------------------------------------------------------------------
__global__ void gsvt_prep(const float* __restrict__ img,
                          const float* __restrict__ Wc,
                          __half* __restrict__ featH,
                          __half* __restrict__ WbH) {
    int tid = blockIdx.x * blockDim.x + threadIdx.x;
    int stride = gridDim.x * blockDim.x;
    const int totF = N_ * H_ * W_ * C_;       // 430080
    for (int i = tid; i < totF; i += stride) {
        int c  = i & 63;
        int hw = i >> 6;
        int w  = hw % W_;
        int nh = hw / W_;
        int h  = nh % H_;
        int n  = nh / H_;
        featH[i] = __float2half(img[((n * C_ + c) * H_ + h) * W_ + w]);
    }
    const int totW = OUTC_ * KD_;             // 65536
    for (int i = tid; i < totW; i += stride) {
        int k = i & (KD_ - 1);
        int o = i >> 9;
        int y = k >> 6;
        int c = k & 63;
        WbH[i] = __float2half(Wc[o * KD_ + c * YC_ + y]);
    }
}

// ===========================================================================
// Fused, quad-corner-lane version.
// Sampling geometry: 32 lanes per (pair, cam): lane = [ch3 | corner2 | half1].
// One VMEM instruction per cam fetches ALL 4 corners (per-lane addresses);
// 4 cams issue back-to-back -> one L2 latency per pair.  pk_fma_f16
// accumulation; shfl_xor butterfly sums corners.  f16 end-to-end.
// Grid: (25, 50), block 256.  LDS = 48 KB -> 3 blocks/CU.
// ===========================================================================
__global__ __launch_bounds__(256, 3) void gsvt_fusedQ(
        const float* __restrict__ coords,        // (N, ZC, YC, XC, 3)
        const float* __restrict__ validm,        // (N, ZC, YC, XC)
        const __half* __restrict__ featH,        // (N, H, W, C) f16
        const __half* __restrict__ WbH,          // (OUTC, 512) f16, y-major k
        const float* __restrict__ bias,          // (OUTC)
        float* __restrict__ out)                 // (OUTC, ZC, XC)
{
    // tab entry (16B): x = w00|w01 (f16x2), y = w10|w11 (f16x2),
    //                  z = base byte offset,  w = dxo | dyo<<16
    __shared__ uint4 tab[N_ * 256];              // 16 KB
    __shared__ unsigned short redB[64][NCOL][8]; // 32 KB (f16 payload)
    float (*ms)[4] = (float(*)[4])&redB[0][0][0];  // 4 KB alias, dead before redB

    const int z0 = blockIdx.y * ZB;
    const int x0 = blockIdx.x * XB;
    const int t  = threadIdx.x;

    // ---- phase 0a: one pair per thread; p0 = y*32 + col, col = zz*8+xl ----
    const int p0   = t;
    const int y0_  = t >> 5;
    const int col0 = t & 31;
    const int zg   = z0 + (col0 >> 3);
    const int xg   = x0 + (col0 & 7);

    float gx[4], gy[4], gzv[4], mm[4];
    #pragma unroll
    for (int cam = 0; cam < N_; ++cam) {
        const int cb = ((cam * ZC_ + zg) * YC_ + y0_) * XC_ + xg;
        gx[cam]  = coords[cb * 3 + 0];
        gy[cam]  = coords[cb * 3 + 1];
        gzv[cam] = coords[cb * 3 + 2];
        mm[cam]  = validm[cb];
        ms[p0][cam] = mm[cam];
    }
    __syncthreads();

    // ---- phase 0b: f16 corner weights (mask, zw, 1/den folded) + offsets ----
    {
        const float inv = 1.0f / (ms[p0][0] + ms[p0][1] + ms[p0][2] + ms[p0][3] + EPS_);
        #pragma unroll
        for (int cam = 0; cam < N_; ++cam) {
            const float xf = ((gx[cam] + 1.0f) * (float)W_ - 1.0f) * 0.5f;
            const float yf = ((gy[cam] + 1.0f) * (float)H_ - 1.0f) * 0.5f;
            const float zf = gzv[cam] * 0.5f;
            const float x0f = floorf(xf), y0f = floorf(yf), z0f = floorf(zf);
            const float wx = xf - x0f, wy = yf - y0f, wz = zf - z0f;
            const int xi = (int)x0f, yi = (int)y0f, zi = (int)z0f;

            const float zw = (zi == 0) ? (1.f - wz) : ((zi == -1) ? wz : 0.f);
            const float s  = mm[cam] * zw * inv;

            const float wx0 = (xi >= 0 && xi < W_)         ? (1.f - wx) * s : 0.f;
            const float wx1 = (xi + 1 >= 0 && xi + 1 < W_) ? wx * s         : 0.f;
            const float wy0 = (yi >= 0 && yi < H_)         ? (1.f - wy)     : 0.f;
            const float wy1 = (yi + 1 >= 0 && yi + 1 < H_) ? wy             : 0.f;

            const unsigned h00 = __half_as_ushort(__float2half(wy0 * wx0));
            const unsigned h01 = __half_as_ushort(__float2half(wy0 * wx1));
            const unsigned h10 = __half_as_ushort(__float2half(wy1 * wx0));
            const unsigned h11 = __half_as_ushort(__float2half(wy1 * wx1));

            const int xc0 = min(max(xi, 0), W_ - 1);
            const int xc1 = min(max(xi + 1, 0), W_ - 1);
            const int yc0 = min(max(yi, 0), H_ - 1);
            const int yc1 = min(max(yi + 1, 0), H_ - 1);
            const unsigned base = (unsigned)((((cam * H_ + yc0) * W_) + xc0) * 128);
            const unsigned dxo  = (unsigned)((xc1 - xc0) * 128);          // 0 or 128
            const unsigned dyo  = (unsigned)((yc1 - yc0) * W_ * 128);     // 0 or 7680
            tab[cam * 256 + p0] = make_uint4(h00 | (h01 << 16), h10 | (h11 << 16),
                                             base, dxo | (dyo << 16));
        }
    }
    __syncthreads();

    // ---- sampling: 32 lanes per pair; lane = [ch3 | corner2 | half1] ----
    const int wv    = t >> 6;        // wave 0..3 -> y range [wv*2, wv*2+2)
    const int l     = t & 63;
    const int hh    = l >> 5;        // pair half
    const int cr    = (l >> 3) & 3;  // corner: bit0 = +dx, bit1 = +dy
    const int lane8 = l & 7;         // channel block
    const unsigned lb = (unsigned)(lane8 << 4);
    const char* fb  = (const char*)featH;
    const int pbase = wv * 64;

    #pragma unroll
    for (int i = 0; i < 32; ++i) {
        const int p = pbase + 2 * i + hh;

        // 4 table reads (broadcast within half)
        uint4 T0 = tab[0 * 256 + p];
        uint4 T1 = tab[1 * 256 + p];
        uint4 T2 = tab[2 * 256 + p];
        uint4 T3 = tab[3 * 256 + p];

        // all-corner loads, one instruction per cam, exec-masked per cam
        uint4 V0 = make_uint4(0,0,0,0), V1 = V0, V2 = V0, V3 = V0;
        #define QLOAD(Vv, Tv)                                                  \
            if (Tv.x | Tv.y) {                                                 \
                const unsigned doff =                                          \
                    ((cr & 1) ? (Tv.w & 0xFFFFu) : 0u) +                       \
                    ((cr & 2) ? (Tv.w >> 16)     : 0u);                        \
                Vv = *(const uint4*)(fb + Tv.z + doff + lb);                   \
            }
        QLOAD(V0, T0) QLOAD(V1, T1) QLOAD(V2, T2) QLOAD(V3, T3)
        #undef QLOAD

        // accumulate: each lane weights its own corner's 8 channels
        __half2 num0 = __half2half2(__ushort_as_half(0));
        __half2 num1 = num0, num2 = num0, num3 = num0;
        #define QACC(Vv, Tv)                                                   \
            if (Tv.x | Tv.y) {                                                 \
                const unsigned ww = (cr & 2) ? Tv.y : Tv.x;                    \
                const unsigned ws = (cr & 1) ? (ww >> 16) : (ww & 0xFFFFu);    \
                const unsigned wp = ws | (ws << 16);                           \
                const __half2 w2 = *(const __half2*)&wp;                       \
                num0 = __hfma2(w2, *(const __half2*)&Vv.x, num0);              \
                num1 = __hfma2(w2, *(const __half2*)&Vv.y, num1);              \
                num2 = __hfma2(w2, *(const __half2*)&Vv.z, num2);              \
                num3 = __hfma2(w2, *(const __half2*)&Vv.w, num3);              \
            }
        QACC(V0, T0) QACC(V1, T1) QACC(V2, T2) QACC(V3, T3)
        #undef QACC

        // butterfly over corner bits (lane xor 8, 16): all lanes get the sum
        unsigned u0 = *(unsigned*)&num0, u1 = *(unsigned*)&num1;
        unsigned u2 = *(unsigned*)&num2, u3 = *(unsigned*)&num3;
        #define BFLY(mask)                                                     \
            {                                                                  \
                unsigned s0 = __shfl_xor((int)u0, mask);                       \
                unsigned s1 = __shfl_xor((int)u1, mask);                       \
                unsigned s2 = __shfl_xor((int)u2, mask);                       \
                unsigned s3 = __shfl_xor((int)u3, mask);                       \
                __half2 a;                                                     \
                a = __hadd2(*(__half2*)&u0, *(__half2*)&s0); u0 = *(unsigned*)&a; \
                a = __hadd2(*(__half2*)&u1, *(__half2*)&s1); u1 = *(unsigned*)&a; \
                a = __hadd2(*(__half2*)&u2, *(__half2*)&s2); u2 = *(unsigned*)&a; \
                a = __hadd2(*(__half2*)&u3, *(__half2*)&s3); u3 = *(unsigned*)&a; \
            }
        BFLY(8) BFLY(16)
        #undef BFLY

        // corner-0 lanes write the pair's 8 channels (16B) to redB
        if (cr == 0) {
            const int yy   = p >> 5;
            const int colp = p & 31;
            const int kb   = yy * 8 + lane8;
            const int pcol = (colp & 16) | ((colp ^ kb) & 15);   // XOR swizzle
            *(uint4*)&redB[kb][pcol][0] = make_uint4(u0, u1, u2, u3);
        }
    }
    __syncthreads();

    // ---- GEMM: C[128,32] = WbH[128,512] * redB[512,32]  (f16 MFMA) ----
    const int wave = t >> 6;        // rows [wave*32, +32)
    const int lane = t & 63;
    const int q    = lane >> 4;
    const int l16  = lane & 15;

    f32x4 acc00 = {0.f,0.f,0.f,0.f}, acc01 = {0.f,0.f,0.f,0.f};
    f32x4 acc10 = {0.f,0.f,0.f,0.f}, acc11 = {0.f,0.f,0.f,0.f};
    const __half* wbase = WbH + (wave * 32 + l16) * KD_;

    #pragma unroll
    for (int ks = 0; ks < 16; ++ks) {
        const int kb = ks * 4 + q;
        const int xs = l16 ^ (kb & 15);
        const half8 B0 = *(const half8*)&redB[kb][xs][0];
        const half8 B1 = *(const half8*)&redB[kb][16 + xs][0];
        const half8 A0 = *(const half8*)(wbase + ks * 32 + q * 8);
        const half8 A1 = *(const half8*)(wbase + 16 * KD_ + ks * 32 + q * 8);
        acc00 = __builtin_amdgcn_mfma_f32_16x16x32_f16(A0, B0, acc00, 0, 0, 0);
        acc01 = __builtin_amdgcn_mfma_f32_16x16x32_f16(A0, B1, acc01, 0, 0, 0);
        acc10 = __builtin_amdgcn_mfma_f32_16x16x32_f16(A1, B0, acc10, 0, 0, 0);
        acc11 = __builtin_amdgcn_mfma_f32_16x16x32_f16(A1, B1, acc11, 0, 0, 0);
    }

    #pragma unroll
    for (int ct = 0; ct < 2; ++ct) {
        const int c2  = ct * 16 + l16;
        const int zz  = c2 >> 3;
        const int xl  = c2 & 7;
        const int ob  = (z0 + zz) * XC_ + x0 + xl;
        const f32x4 a0 = ct ? acc01 : acc00;
        const f32x4 a1 = ct ? acc11 : acc10;
        #pragma unroll
        for (int j = 0; j < 4; ++j) {
            const int o0 = wave * 32 + q * 4 + j;
            out[o0 * (ZC_ * XC_) + ob] = a0[j] + bias[o0];
            const int o1 = o0 + 16;
            out[o1 * (ZC_ * XC_) + ob] = a1[j] + bias[o1];
        }
    }
}

extern "C" void kernel_launch(void* const* d_in, const int* in_sizes, int n_in,
                              void* d_out, int out_size, void* d_ws, size_t ws_size,
                              hipStream_t stream) {
    const float* coords = (const float*)d_in[0];   // (1,4,200,8,200,3)
    const float* validm = (const float*)d_in[1];   // (1,4,200,8,200,1)
    const float* img    = (const float*)d_in[2];   // (1,4,64,28,60)
    const float* Wc     = (const float*)d_in[3];   // (128, 512)
    const float* bias   = (const float*)d_in[4];   // (128)
    float* out = (float*)d_out;                    // (1,1,128,200,200)

    __half* featH = (__half*)d_ws;                 // 430080 f16
    __half* WbH   = featH + (N_ * H_ * W_ * C_);   // 65536 f16

    gsvt_prep<<<512, 256, 0, stream>>>(img, Wc, featH, WbH);

    dim3 grid(XC_ / XB, ZC_ / ZB);   // (25, 50)
    gsvt_fusedQ<<<grid, 256, 0, stream>>>(coords, validm, featH, WbH, bias, out);
}

// Round 14
// 56.427 us; speedup vs baseline: 1.2312x; 1.2312x over previous
//
#include <hip/hip_runtime.h>
#include <hip/hip_bf16.h>
#include <hip/hip_fp16.h>

#define N_  4
#define C_  64
#define H_  28
#define W_  60
#define ZC_ 200
#define YC_ 8
#define XC_ 200
#define OUTC_ 128
#define KD_ 512            // C_*YC_
#define EPS_ 1e-6f
#define ZB 4               // z slices per block
#define XB 8               // x positions per block
#define NCOL 32            // ZB*XB columns per block

typedef __attribute__((ext_vector_type(8))) short short8;
typedef __attribute__((ext_vector_type(4))) float f32x4;
typedef __attribute__((ext_vector_type(4))) unsigned int u32x4;

__device__ __forceinline__ unsigned short f2bf(float f) {
    unsigned int u = __float_as_uint(f);
    u += 0x7FFF + ((u >> 16) & 1);   // round-to-nearest-even
    return (unsigned short)(u >> 16);
}

// ---------------------------------------------------------------------------
// Prep: featB[n][h][w][c] = bf16(img[n][c][h][w])  (channels-last, bf16)
//       Wb[o][y*64+c]     = bf16(W[o][c*8+y])      (y-major k, bf16)
// ---------------------------------------------------------------------------
__global__ void gsvt_prep(const float* __restrict__ img,
                          const float* __restrict__ Wc,
                          unsigned short* __restrict__ featB,
                          unsigned short* __restrict__ Wb) {
    int tid = blockIdx.x * blockDim.x + threadIdx.x;
    int stride = gridDim.x * blockDim.x;
    const int totF = N_ * H_ * W_ * C_;       // 430080
    for (int i = tid; i < totF; i += stride) {
        int c  = i & 63;
        int hw = i >> 6;
        int w  = hw % W_;
        int nh = hw / W_;
        int h  = nh % H_;
        int n  = nh / H_;
        featB[i] = f2bf(img[((n * C_ + c) * H_ + h) * W_ + w]);
    }
    const int totW = OUTC_ * KD_;             // 65536
    for (int i = tid; i < totW; i += stride) {
        int k = i & (KD_ - 1);
        int o = i >> 9;
        int y = k >> 6;
        int c = k & 63;
        Wb[i] = f2bf(Wc[o * KD_ + c * YC_ + y]);
    }
}

// float2 accumulate of one corner (8 channels), weight w broadcast.
__device__ __forceinline__ void accp(float2* n, const u32x4 V, const float w) {
    float2 f0, f1, f2, f3;
    f0.x = __uint_as_float(V.x << 16); f0.y = __uint_as_float(V.x & 0xFFFF0000u);
    f1.x = __uint_as_float(V.y << 16); f1.y = __uint_as_float(V.y & 0xFFFF0000u);
    f2.x = __uint_as_float(V.z << 16); f2.y = __uint_as_float(V.z & 0xFFFF0000u);
    f3.x = __uint_as_float(V.w << 16); f3.y = __uint_as_float(V.w & 0xFFFF0000u);
    n[0].x += w * f0.x; n[0].y += w * f0.y;
    n[1].x += w * f1.x; n[1].y += w * f1.y;
    n[2].x += w * f2.x; n[2].y += w * f2.y;
    n[3].x += w * f3.x; n[3].y += w * f3.y;
}

// ===========================================================================
// Fused: phase0 (8B-packed tables) -> asm-batched gather (16 loads in flight,
// counted vmcnt) -> in-block GEMM C[128,32] = Wb[128,512] * redB[512,32].
// Grid: (25, 50), block 256.  LDS = 40 KB.
// ===========================================================================
__global__ __launch_bounds__(256, 3) void gsvt_fusedA(
        const float* __restrict__ coords,        // (N, ZC, YC, XC, 3)
        const float* __restrict__ validm,        // (N, ZC, YC, XC)
        const unsigned short* __restrict__ featB,// (N, H, W, C) bf16
        const unsigned short* __restrict__ Wb,   // (OUTC, 512) bf16, y-major k
        const float* __restrict__ bias,          // (OUTC)
        float* __restrict__ out)                 // (OUTC, ZC, XC)
{
    // tab2 entry (8B): A = q00 | q01<<12 | q10.lo8<<24
    //                  B = q10.hi4 | q11<<4 | pixidx<<16 | fdx<<29 | fdy<<30
    __shared__ uint2 tab2[N_ * 256];             // 8 KB
    __shared__ unsigned short redB[64][NCOL][8]; // 32 KB
    float (*ms)[4] = (float(*)[4])&redB[0][0][0];  // 4 KB alias (dead before redB)

    const int z0 = blockIdx.y * ZB;
    const int x0 = blockIdx.x * XB;
    const int t  = threadIdx.x;

    // ---- phase 0a ----
    const int p0   = t;
    const int y0_  = t >> 5;
    const int col0 = t & 31;
    const int zg   = z0 + (col0 >> 3);
    const int xg   = x0 + (col0 & 7);

    float gx[4], gy[4], gzv[4], mm[4];
    #pragma unroll
    for (int cam = 0; cam < N_; ++cam) {
        const int cb = ((cam * ZC_ + zg) * YC_ + y0_) * XC_ + xg;
        gx[cam]  = coords[cb * 3 + 0];
        gy[cam]  = coords[cb * 3 + 1];
        gzv[cam] = coords[cb * 3 + 2];
        mm[cam]  = validm[cb];
        ms[p0][cam] = mm[cam];
    }
    __syncthreads();

    // ---- phase 0b: packed weights + offsets ----
    {
        const float inv = 1.0f / (ms[p0][0] + ms[p0][1] + ms[p0][2] + ms[p0][3] + EPS_);
        #pragma unroll
        for (int cam = 0; cam < N_; ++cam) {
            const float xf = ((gx[cam] + 1.0f) * (float)W_ - 1.0f) * 0.5f;
            const float yf = ((gy[cam] + 1.0f) * (float)H_ - 1.0f) * 0.5f;
            const float zf = gzv[cam] * 0.5f;
            const float x0f = floorf(xf), y0f = floorf(yf), z0f = floorf(zf);
            const float wx = xf - x0f, wy = yf - y0f, wz = zf - z0f;
            const int xi = (int)x0f, yi = (int)y0f, zi = (int)z0f;

            const float zw = (zi == 0) ? (1.f - wz) : ((zi == -1) ? wz : 0.f);
            const float s  = mm[cam] * zw * inv;

            const float wx0 = (xi >= 0 && xi < W_)         ? (1.f - wx) * s : 0.f;
            const float wx1 = (xi + 1 >= 0 && xi + 1 < W_) ? wx * s         : 0.f;
            const float wy0 = (yi >= 0 && yi < H_)         ? (1.f - wy)     : 0.f;
            const float wy1 = (yi + 1 >= 0 && yi + 1 < H_) ? wy             : 0.f;

            const unsigned q00 = (unsigned)(wy0 * wx0 * 4095.f + 0.5f);
            const unsigned q01 = (unsigned)(wy0 * wx1 * 4095.f + 0.5f);
            const unsigned q10 = (unsigned)(wy1 * wx0 * 4095.f + 0.5f);
            const unsigned q11 = (unsigned)(wy1 * wx1 * 4095.f + 0.5f);

            const int xc0 = min(max(xi, 0), W_ - 1);
            const int xc1 = min(max(xi + 1, 0), W_ - 1);
            const int yc0 = min(max(yi, 0), H_ - 1);
            const int yc1 = min(max(yi + 1, 0), H_ - 1);
            const unsigned pixidx = (unsigned)((cam * H_ + yc0) * W_ + xc0);  // <6720
            const unsigned fdx = (unsigned)(xc1 - xc0);   // 0/1
            const unsigned fdy = (unsigned)(yc1 - yc0);   // 0/1

            const unsigned A = q00 | (q01 << 12) | ((q10 & 0xFFu) << 24);
            const unsigned B = (q10 >> 8) | (q11 << 4) | (pixidx << 16)
                             | (fdx << 29) | (fdy << 30);
            tab2[cam * 256 + p0] = make_uint2(A, B);
        }
    }
    __syncthreads();

    // ---- sampling: 32 groups of 8 lanes; asm-batched 16-load gather ----
    const int grp   = t >> 3;        // column 0..31
    const int lane8 = t & 7;
    const unsigned lb = (unsigned)(lane8 << 4);
    const char* fb = (const char*)featB;

    #define ISSUE(V, A_) asm volatile("global_load_dwordx4 %0, %1, off" \
                                      : "=v"(V) : "v"(A_))
    #define WAITV(n) do { asm volatile("s_waitcnt vmcnt(" #n ")"); \
                          __builtin_amdgcn_sched_barrier(0); } while (0)

    #pragma unroll
    for (int y = 0; y < YC_; ++y) {
        const int p = y * 32 + grp;

        // table entries for all 4 cams (LDS, lgkmcnt handled by compiler)
        const uint2 T0 = tab2[0 * 256 + p];
        const uint2 T1 = tab2[1 * 256 + p];
        const uint2 T2 = tab2[2 * 256 + p];
        const uint2 T3 = tab2[3 * 256 + p];

        // per-cam predicated addresses (inactive -> offset 0, one hot line)
        u32x4 V00, V01, V02, V03, V10, V11, V12, V13;
        u32x4 V20, V21, V22, V23, V30, V31, V32, V33;
        #define ADDR_ISSUE(Tv, Va, Vb, Vc, Vd)                                 \
            {                                                                  \
                const bool act = (Tv.x | (Tv.y & 0xFFFFu)) != 0u;              \
                const unsigned base = act ? ((((Tv.y >> 16) & 0x1FFFu) << 7) + lb) : lb; \
                const unsigned dxo  = act ? (((Tv.y >> 29) & 1u) << 7) : 0u;   \
                const unsigned dyo  = act ? (((Tv.y >> 30) & 1u) * (unsigned)(W_ * 128)) : 0u; \
                ISSUE(Va, fb + base);                                          \
                ISSUE(Vb, fb + (base + dxo));                                  \
                ISSUE(Vc, fb + (base + dyo));                                  \
                ISSUE(Vd, fb + (base + dyo + dxo));                            \
            }
        ADDR_ISSUE(T0, V00, V01, V02, V03)
        ADDR_ISSUE(T1, V10, V11, V12, V13)
        ADDR_ISSUE(T2, V20, V21, V22, V23)
        ADDR_ISSUE(T3, V30, V31, V32, V33)
        #undef ADDR_ISSUE

        float2 num[4] = {{0.f,0.f},{0.f,0.f},{0.f,0.f},{0.f,0.f}};

        #define DECW(Tv, w00, w01, w10, w11)                                   \
            const float w00 = (float)(Tv.x & 0xFFFu)                        * (1.f/4095.f); \
            const float w01 = (float)((Tv.x >> 12) & 0xFFFu)                * (1.f/4095.f); \
            const float w10 = (float)((Tv.x >> 24) | ((Tv.y & 0xFu) << 8)) * (1.f/4095.f); \
            const float w11 = (float)((Tv.y >> 4) & 0xFFFu)                 * (1.f/4095.f);

        { DECW(T0, a, b, c, d) WAITV(12);
          accp(num, V00, a); accp(num, V01, b); accp(num, V02, c); accp(num, V03, d); }
        { DECW(T1, a, b, c, d) WAITV(8);
          accp(num, V10, a); accp(num, V11, b); accp(num, V12, c); accp(num, V13, d); }
        { DECW(T2, a, b, c, d) WAITV(4);
          accp(num, V20, a); accp(num, V21, b); accp(num, V22, c); accp(num, V23, d); }
        { DECW(T3, a, b, c, d) WAITV(0);
          accp(num, V30, a); accp(num, V31, b); accp(num, V32, c); accp(num, V33, d); }
        #undef DECW

        unsigned r0, r1, r2, r3;
        asm("v_cvt_pk_bf16_f32 %0, %1, %2" : "=v"(r0) : "v"(num[0].x), "v"(num[0].y));
        asm("v_cvt_pk_bf16_f32 %0, %1, %2" : "=v"(r1) : "v"(num[1].x), "v"(num[1].y));
        asm("v_cvt_pk_bf16_f32 %0, %1, %2" : "=v"(r2) : "v"(num[2].x), "v"(num[2].y));
        asm("v_cvt_pk_bf16_f32 %0, %1, %2" : "=v"(r3) : "v"(num[3].x), "v"(num[3].y));

        const int kb   = y * 8 + lane8;
        const int pcol = (grp & 16) | ((grp ^ kb) & 15);   // XOR swizzle
        *(uint4*)&redB[kb][pcol][0] = make_uint4(r0, r1, r2, r3);
    }
    #undef ISSUE
    #undef WAITV
    __syncthreads();

    // ---- GEMM: C[128,32] = Wb[128,512] * redB[512,32] ----
    const int wave = t >> 6;        // rows [wave*32, +32)
    const int lane = t & 63;
    const int q    = lane >> 4;
    const int l16  = lane & 15;

    f32x4 acc00 = {0.f,0.f,0.f,0.f}, acc01 = {0.f,0.f,0.f,0.f};
    f32x4 acc10 = {0.f,0.f,0.f,0.f}, acc11 = {0.f,0.f,0.f,0.f};
    const unsigned short* wbase = Wb + (wave * 32 + l16) * KD_;

    #pragma unroll
    for (int ks = 0; ks < 16; ++ks) {
        const int kb = ks * 4 + q;
        const int xs = l16 ^ (kb & 15);
        const short8 B0 = *(const short8*)&redB[kb][xs][0];
        const short8 B1 = *(const short8*)&redB[kb][16 + xs][0];
        const short8 A0 = *(const short8*)(wbase + ks * 32 + q * 8);
        const short8 A1 = *(const short8*)(wbase + 16 * KD_ + ks * 32 + q * 8);
        acc00 = __builtin_amdgcn_mfma_f32_16x16x32_bf16(A0, B0, acc00, 0, 0, 0);
        acc01 = __builtin_amdgcn_mfma_f32_16x16x32_bf16(A0, B1, acc01, 0, 0, 0);
        acc10 = __builtin_amdgcn_mfma_f32_16x16x32_bf16(A1, B0, acc10, 0, 0, 0);
        acc11 = __builtin_amdgcn_mfma_f32_16x16x32_bf16(A1, B1, acc11, 0, 0, 0);
    }

    #pragma unroll
    for (int ct = 0; ct < 2; ++ct) {
        const int c2  = ct * 16 + l16;
        const int zz  = c2 >> 3;
        const int xl  = c2 & 7;
        const int ob  = (z0 + zz) * XC_ + x0 + xl;
        const f32x4 a0 = ct ? acc01 : acc00;
        const f32x4 a1 = ct ? acc11 : acc10;
        #pragma unroll
        for (int j = 0; j < 4; ++j) {
            const int o0 = wave * 32 + q * 4 + j;
            out[o0 * (ZC_ * XC_) + ob] = a0[j] + bias[o0];
            const int o1 = o0 + 16;
            out[o1 * (ZC_ * XC_) + ob] = a1[j] + bias[o1];
        }
    }
}

extern "C" void kernel_launch(void* const* d_in, const int* in_sizes, int n_in,
                              void* d_out, int out_size, void* d_ws, size_t ws_size,
                              hipStream_t stream) {
    const float* coords = (const float*)d_in[0];   // (1,4,200,8,200,3)
    const float* validm = (const float*)d_in[1];   // (1,4,200,8,200,1)
    const float* img    = (const float*)d_in[2];   // (1,4,64,28,60)
    const float* Wc     = (const float*)d_in[3];   // (128, 512)
    const float* bias   = (const float*)d_in[4];   // (128)
    float* out = (float*)d_out;                    // (1,1,128,200,200)

    unsigned short* featB = (unsigned short*)d_ws;           // 430080 bf16
    unsigned short* Wb    = featB + (N_ * H_ * W_ * C_);     // 65536 bf16

    gsvt_prep<<<512, 256, 0, stream>>>(img, Wc, featB, Wb);

    dim3 grid(XC_ / XB, ZC_ / ZB);   // (25, 50)
    gsvt_fusedA<<<grid, 256, 0, stream>>>(coords, validm, featB, Wb, bias, out);
}

// Round 16
// 54.979 us; speedup vs baseline: 1.2637x; 1.0263x over previous
//
#include <hip/hip_runtime.h>
#include <hip/hip_bf16.h>
#include <hip/hip_fp16.h>

#define N_  4
#define C_  64
#define H_  28
#define W_  60
#define ZC_ 200
#define YC_ 8
#define XC_ 200
#define OUTC_ 128
#define KD_ 512            // C_*YC_
#define EPS_ 1e-6f
#define ZB 4               // z slices per block
#define XB 8               // x positions per block
#define NCOL 32            // ZB*XB columns per block

typedef __attribute__((ext_vector_type(8))) _Float16 half8;
typedef __attribute__((ext_vector_type(4))) float f32x4;
typedef __attribute__((ext_vector_type(4))) unsigned int u32x4;

// ---------------------------------------------------------------------------
// Prep: featH[n][h][w][c] = f16(img[n][c][h][w])  (channels-last, f16)
//       WbH[o][y*64+c]    = f16(W[o][c*8+y])      (y-major k, f16)
// ---------------------------------------------------------------------------
__global__ void gsvt_prep(const float* __restrict__ img,
                          const float* __restrict__ Wc,
                          __half* __restrict__ featH,
                          __half* __restrict__ WbH) {
    int tid = blockIdx.x * blockDim.x + threadIdx.x;
    int stride = gridDim.x * blockDim.x;
    const int totF = N_ * H_ * W_ * C_;       // 430080
    for (int i = tid; i < totF; i += stride) {
        int c  = i & 63;
        int hw = i >> 6;
        int w  = hw % W_;
        int nh = hw / W_;
        int h  = nh % H_;
        int n  = nh / H_;
        featH[i] = __float2half(img[((n * C_ + c) * H_ + h) * W_ + w]);
    }
    const int totW = OUTC_ * KD_;             // 65536
    for (int i = tid; i < totW; i += stride) {
        int k = i & (KD_ - 1);
        int o = i >> 9;
        int y = k >> 6;
        int c = k & 63;
        WbH[i] = __float2half(Wc[o * KD_ + c * YC_ + y]);
    }
}

// f16 accumulate of one corner (8 channels in u32x4), broadcast weight wp.
__device__ __forceinline__ void accq(__half2* n, const u32x4 V, const unsigned wp) {
    const __half2 w2 = *(const __half2*)&wp;
    unsigned vx = V.x, vy = V.y, vz = V.z, vw = V.w;
    n[0] = __hfma2(w2, *(const __half2*)&vx, n[0]);
    n[1] = __hfma2(w2, *(const __half2*)&vy, n[1]);
    n[2] = __hfma2(w2, *(const __half2*)&vz, n[2]);
    n[3] = __hfma2(w2, *(const __half2*)&vw, n[3]);
}

// ===========================================================================
// Fused: phase0 (f16-weight tables) -> asm-batched gather (16 loads in
// flight, counted vmcnt) with hfma2 accumulation -> in-block f16 GEMM
// C[128,32] = WbH[128,512] * redB[512,32].
// Grid: (25, 50), block 256.  LDS = 48 KB -> 3 blocks/CU.
// ===========================================================================
__global__ __launch_bounds__(256, 3) void gsvt_fusedF(
        const float* __restrict__ coords,        // (N, ZC, YC, XC, 3)
        const float* __restrict__ validm,        // (N, ZC, YC, XC)
        const __half* __restrict__ featH,        // (N, H, W, C) f16
        const __half* __restrict__ WbH,          // (OUTC, 512) f16, y-major k
        const float* __restrict__ bias,          // (OUTC)
        float* __restrict__ out)                 // (OUTC, ZC, XC)
{
    // tab entry (16B): x = w00|w01 (f16x2), y = w10|w11 (f16x2),
    //                  z = base byte offset, w = dxo | dyo<<16
    __shared__ uint4 tab[N_ * 256];              // 16 KB
    __shared__ unsigned short redB[64][NCOL][8]; // 32 KB (f16 payload)
    float (*ms)[4] = (float(*)[4])&redB[0][0][0];  // 4 KB alias (dead before redB)

    const int z0 = blockIdx.y * ZB;
    const int x0 = blockIdx.x * XB;
    const int t  = threadIdx.x;

    // ---- phase 0a: one pair per thread; p0 = y*32 + col, col = zz*8+xl ----
    const int p0   = t;
    const int y0_  = t >> 5;
    const int col0 = t & 31;
    const int zg   = z0 + (col0 >> 3);
    const int xg   = x0 + (col0 & 7);

    float gx[4], gy[4], gzv[4], mm[4];
    #pragma unroll
    for (int cam = 0; cam < N_; ++cam) {
        const int cb = ((cam * ZC_ + zg) * YC_ + y0_) * XC_ + xg;
        gx[cam]  = coords[cb * 3 + 0];
        gy[cam]  = coords[cb * 3 + 1];
        gzv[cam] = coords[cb * 3 + 2];
        mm[cam]  = validm[cb];
        ms[p0][cam] = mm[cam];
    }
    __syncthreads();

    // ---- phase 0b: f16 corner weights (mask, zw, 1/den folded) + offsets ----
    {
        const float inv = 1.0f / (ms[p0][0] + ms[p0][1] + ms[p0][2] + ms[p0][3] + EPS_);
        #pragma unroll
        for (int cam = 0; cam < N_; ++cam) {
            const float xf = ((gx[cam] + 1.0f) * (float)W_ - 1.0f) * 0.5f;
            const float yf = ((gy[cam] + 1.0f) * (float)H_ - 1.0f) * 0.5f;
            const float zf = gzv[cam] * 0.5f;
            const float x0f = floorf(xf), y0f = floorf(yf), z0f = floorf(zf);
            const float wx = xf - x0f, wy = yf - y0f, wz = zf - z0f;
            const int xi = (int)x0f, yi = (int)y0f, zi = (int)z0f;

            const float zw = (zi == 0) ? (1.f - wz) : ((zi == -1) ? wz : 0.f);
            const float s  = mm[cam] * zw * inv;

            const float wx0 = (xi >= 0 && xi < W_)         ? (1.f - wx) * s : 0.f;
            const float wx1 = (xi + 1 >= 0 && xi + 1 < W_) ? wx * s         : 0.f;
            const float wy0 = (yi >= 0 && yi < H_)         ? (1.f - wy)     : 0.f;
            const float wy1 = (yi + 1 >= 0 && yi + 1 < H_) ? wy             : 0.f;

            const unsigned h00 = __half_as_ushort(__float2half(wy0 * wx0));
            const unsigned h01 = __half_as_ushort(__float2half(wy0 * wx1));
            const unsigned h10 = __half_as_ushort(__float2half(wy1 * wx0));
            const unsigned h11 = __half_as_ushort(__float2half(wy1 * wx1));

            const int xc0 = min(max(xi, 0), W_ - 1);
            const int xc1 = min(max(xi + 1, 0), W_ - 1);
            const int yc0 = min(max(yi, 0), H_ - 1);
            const int yc1 = min(max(yi + 1, 0), H_ - 1);
            const unsigned base = (unsigned)((((cam * H_ + yc0) * W_) + xc0) * 128);
            const unsigned dxo  = (unsigned)((xc1 - xc0) * 128);          // 0 or 128
            const unsigned dyo  = (unsigned)((yc1 - yc0) * W_ * 128);     // 0 or 7680
            tab[cam * 256 + p0] = make_uint4(h00 | (h01 << 16), h10 | (h11 << 16),
                                             base, dxo | (dyo << 16));
        }
    }
    __syncthreads();

    // ---- sampling: 32 groups of 8 lanes; asm-batched 16-load gather ----
    const int grp   = t >> 3;        // column 0..31
    const int lane8 = t & 7;
    const unsigned lb = (unsigned)(lane8 << 4);
    const char* fb = (const char*)featH;

    #define ISSUE(V, A_) asm volatile("global_load_dwordx4 %0, %1, off" \
                                      : "=v"(V) : "v"(A_))
    #define WAITV(n) do { asm volatile("s_waitcnt vmcnt(" #n ")"); \
                          __builtin_amdgcn_sched_barrier(0); } while (0)

    #pragma unroll
    for (int y = 0; y < YC_; ++y) {
        const int p = y * 32 + grp;

        const uint4 T0 = tab[0 * 256 + p];
        const uint4 T1 = tab[1 * 256 + p];
        const uint4 T2 = tab[2 * 256 + p];
        const uint4 T3 = tab[3 * 256 + p];

        // per-cam predicated addresses (inactive -> offset 0, one hot line)
        u32x4 V00, V01, V02, V03, V10, V11, V12, V13;
        u32x4 V20, V21, V22, V23, V30, V31, V32, V33;
        #define ADDR_ISSUE(Tv, Va, Vb, Vc, Vd)                                 \
            {                                                                  \
                const bool act = (Tv.x | Tv.y) != 0u;                          \
                const unsigned base = act ? (Tv.z + lb) : lb;                  \
                const unsigned dxo  = act ? (Tv.w & 0xFFFFu) : 0u;             \
                const unsigned dyo  = act ? (Tv.w >> 16) : 0u;                 \
                ISSUE(Va, fb + base);                                          \
                ISSUE(Vb, fb + (base + dxo));                                  \
                ISSUE(Vc, fb + (base + dyo));                                  \
                ISSUE(Vd, fb + (base + dyo + dxo));                            \
            }
        ADDR_ISSUE(T0, V00, V01, V02, V03)
        ADDR_ISSUE(T1, V10, V11, V12, V13)
        ADDR_ISSUE(T2, V20, V21, V22, V23)
        ADDR_ISSUE(T3, V30, V31, V32, V33)
        #undef ADDR_ISSUE

        __half2 zz2 = __half2half2(__ushort_as_half(0));
        __half2 num[4] = {zz2, zz2, zz2, zz2};

        // broadcast helpers: wp = halfword replicated
        #define BLO(u) (((u) & 0xFFFFu) | ((u) << 16))
        #define BHI(u) (((u) & 0xFFFF0000u) | ((u) >> 16))

        WAITV(12);
        accq(num, V00, BLO(T0.x)); accq(num, V01, BHI(T0.x));
        accq(num, V02, BLO(T0.y)); accq(num, V03, BHI(T0.y));
        WAITV(8);
        accq(num, V10, BLO(T1.x)); accq(num, V11, BHI(T1.x));
        accq(num, V12, BLO(T1.y)); accq(num, V13, BHI(T1.y));
        WAITV(4);
        accq(num, V20, BLO(T2.x)); accq(num, V21, BHI(T2.x));
        accq(num, V22, BLO(T2.y)); accq(num, V23, BHI(T2.y));
        WAITV(0);
        accq(num, V30, BLO(T3.x)); accq(num, V31, BHI(T3.x));
        accq(num, V32, BLO(T3.y)); accq(num, V33, BHI(T3.y));
        #undef BLO
        #undef BHI

        const int kb   = y * 8 + lane8;
        const int pcol = (grp & 16) | ((grp ^ kb) & 15);   // XOR swizzle
        *(uint4*)&redB[kb][pcol][0] =
            make_uint4(*(unsigned*)&num[0], *(unsigned*)&num[1],
                       *(unsigned*)&num[2], *(unsigned*)&num[3]);
    }
    #undef ISSUE
    #undef WAITV
    __syncthreads();

    // ---- GEMM: C[128,32] = WbH[128,512] * redB[512,32]  (f16 MFMA) ----
    const int wave = t >> 6;        // rows [wave*32, +32)
    const int lane = t & 63;
    const int q    = lane >> 4;
    const int l16  = lane & 15;

    f32x4 acc00 = {0.f,0.f,0.f,0.f}, acc01 = {0.f,0.f,0.f,0.f};
    f32x4 acc10 = {0.f,0.f,0.f,0.f}, acc11 = {0.f,0.f,0.f,0.f};
    const __half* wbase = WbH + (wave * 32 + l16) * KD_;

    #pragma unroll
    for (int ks = 0; ks < 16; ++ks) {
        const int kb = ks * 4 + q;
        const int xs = l16 ^ (kb & 15);
        const half8 B0 = *(const half8*)&redB[kb][xs][0];
        const half8 B1 = *(const half8*)&redB[kb][16 + xs][0];
        const half8 A0 = *(const half8*)(wbase + ks * 32 + q * 8);
        const half8 A1 = *(const half8*)(wbase + 16 * KD_ + ks * 32 + q * 8);
        acc00 = __builtin_amdgcn_mfma_f32_16x16x32_f16(A0, B0, acc00, 0, 0, 0);
        acc01 = __builtin_amdgcn_mfma_f32_16x16x32_f16(A0, B1, acc01, 0, 0, 0);
        acc10 = __builtin_amdgcn_mfma_f32_16x16x32_f16(A1, B0, acc10, 0, 0, 0);
        acc11 = __builtin_amdgcn_mfma_f32_16x16x32_f16(A1, B1, acc11, 0, 0, 0);
    }

    #pragma unroll
    for (int ct = 0; ct < 2; ++ct) {
        const int c2  = ct * 16 + l16;
        const int zz  = c2 >> 3;
        const int xl  = c2 & 7;
        const int ob  = (z0 + zz) * XC_ + x0 + xl;
        const f32x4 a0 = ct ? acc01 : acc00;
        const f32x4 a1 = ct ? acc11 : acc10;
        #pragma unroll
        for (int j = 0; j < 4; ++j) {
            const int o0 = wave * 32 + q * 4 + j;
            out[o0 * (ZC_ * XC_) + ob] = a0[j] + bias[o0];
            const int o1 = o0 + 16;
            out[o1 * (ZC_ * XC_) + ob] = a1[j] + bias[o1];
        }
    }
}

extern "C" void kernel_launch(void* const* d_in, const int* in_sizes, int n_in,
                              void* d_out, int out_size, void* d_ws, size_t ws_size,
                              hipStream_t stream) {
    const float* coords = (const float*)d_in[0];   // (1,4,200,8,200,3)
    const float* validm = (const float*)d_in[1];   // (1,4,200,8,200,1)
    const float* img    = (const float*)d_in[2];   // (1,4,64,28,60)
    const float* Wc     = (const float*)d_in[3];   // (128, 512)
    const float* bias   = (const float*)d_in[4];   // (128)
    float* out = (float*)d_out;                    // (1,1,128,200,200)

    __half* featH = (__half*)d_ws;                 // 430080 f16
    __half* WbH   = featH + (N_ * H_ * W_ * C_);   // 65536 f16

    gsvt_prep<<<512, 256, 0, stream>>>(img, Wc, featH, WbH);

    dim3 grid(XC_ / XB, ZC_ / ZB);   // (25, 50)
    gsvt_fusedF<<<grid, 256, 0, stream>>>(coords, validm, featH, WbH, bias, out);
}